// Round 4
// baseline (85.948 us; speedup 1.0000x reference)
//
#include <hip/hip_runtime.h>

// SlotAttention: B=8, L=256, D=256, K=64
// out[b,i,:] = concat(inputs[b,i,:], context[b,i,:])
// scores[b,i,j] = sum_k W2[k]*tanh(qi[b,i,k]+kj[b,j,k]); attn = softmax_j; ctx = attn @ inputs[b]
//
// Round-4:
//   tanh(q+k) = (tq+tk)/(1+tq*tk) = c + (1-c^2)/(tq+c),  c = 1/tk
//   => score_i = C_j + sum_k B_k * rcp(tq_ik + c_k)
//      with c_k, B_k = w_k(1-c_k^2), C_j = sum_k w_k c_k precomputed in proj.
//   Phase-1 inner is now {add, rcp, fma} per element (was add,fma,rcp,mul,fma).
//   proj: 256 blocks x 256 thr x 8 rows (halves W1 L2 traffic, 4-acc ILP).

#define Bn 8
#define Ln 256
#define Dn 256
#define Kn 64
#define ROWS (Bn*Ln)       // 2048
#define IPB 4              // query rows per block in attn kernel

#define TKMIN 9.765625e-4f     // 2^-10: keep |tk| away from 0 (c = 1/tk bounded)
#define TMAX  0.99999988f      // 1 - 2^-23ish: keep tq + c away from 0

// ---------------- Kernel A: projection + tanh + score-form constants -------
// TQ[row][k]  = clamp(tanh(qi))
// CB[row][0:64] = c = 1/clamp(tanh(kj)); CB[row][64:128] = B = w*(1-c^2)
// Cj[row]     = sum_k w_k * c_k
__global__ __launch_bounds__(256) void proj_kernel(
    const float* __restrict__ X,    // (2048,256)
    const float* __restrict__ W1,   // (64,512)
    const float* __restrict__ W2,   // (64,)
    float* __restrict__ TQ,         // (2048,64)
    float* __restrict__ CB,         // (2048,128)
    float* __restrict__ Cj)         // (2048,)
{
    __shared__ float Xs[8 * 256];   // 8 KB
    const int tid = threadIdx.x;
    const int r0 = blockIdx.x * 8;

    // stage 8 rows (512 float4) with 256 threads, coalesced
    const float4* Xg4 = (const float4*)(X + r0 * Dn);
    float4* Xs4 = (float4*)Xs;
    Xs4[tid]       = Xg4[tid];
    Xs4[tid + 256] = Xg4[tid + 256];
    __syncthreads();

    // wave 0: half=0 rows 0-3 | wave 1: half=1 rows 0-3
    // wave 2: half=0 rows 4-7 | wave 3: half=1 rows 4-7   (half wave-uniform)
    const int kk = tid & 63, half = (tid >> 6) & 1, rg = tid >> 7;
    const float w2k = W2[kk];
    const float4* Wrow = (const float4*)(W1 + kk * (2 * Dn) + half * Dn);
    float acc[4] = {0, 0, 0, 0};
    #pragma unroll 8
    for (int d4 = 0; d4 < 64; ++d4) {
        float4 w = Wrow[d4];
        #pragma unroll
        for (int r = 0; r < 4; ++r) {
            float4 x = ((const float4*)(Xs + (rg * 4 + r) * Dn))[d4];  // broadcast
            float a = acc[r];
            a = fmaf(w.x, x.x, a);
            a = fmaf(w.y, x.y, a);
            a = fmaf(w.z, x.z, a);
            a = fmaf(w.w, x.w, a);
            acc[r] = a;
        }
    }
    #pragma unroll
    for (int r = 0; r < 4; ++r) {
        const int row = r0 + rg * 4 + r;
        float e = __expf(2.0f * acc[r]);
        float t = 1.0f - 2.0f / (e + 1.0f);
        t = fminf(TMAX, fmaxf(-TMAX, t));
        if (half == 0) {
            TQ[row * Kn + kk] = t;             // coalesced 256B store
        } else {
            float tk = (fabsf(t) < TKMIN) ? copysignf(TKMIN, t) : t;
            float c  = __builtin_amdgcn_rcpf(tk);
            float wc = w2k * c;
            float Bv = fmaf(-wc, c, w2k);      // w*(1 - c^2)
            CB[row * 128 + kk]      = c;
            CB[row * 128 + 64 + kk] = Bv;
            // wave-reduce sum_k wc -> Cj[row]
            float vsum = wc;
            #pragma unroll
            for (int off = 32; off > 0; off >>= 1)
                vsum += __shfl_xor(vsum, off);
            if (kk == 0) Cj[row] = vsum;
        }
    }
}

// ---------------- Kernel B: scores + softmax + context ----------------
// grid = (B*L/IPB) blocks, 256 threads. Block handles rows i0..i0+3 of batch b.
__global__ __launch_bounds__(256, 2) void attn_kernel(
    const float* __restrict__ X,    // (2048,256)
    const float* __restrict__ TQ,   // (2048,64)
    const float* __restrict__ CB,   // (2048,128)
    const float* __restrict__ Cj,   // (2048,)
    float* __restrict__ out)        // (2048,512)
{
    __shared__ float tq_s[IPB * Kn];        // [i][k], 1 KB
    __shared__ float S[Ln * IPB];           // [j][i], 4 KB
    __shared__ float4 red[4 * IPB * 64];    // [wv][i][dquad], 16 KB

    const int tid = threadIdx.x;
    const int b  = blockIdx.x / (Ln / IPB);
    const int i0 = (blockIdx.x % (Ln / IPB)) * IPB;

    {   // tq for the 4 query rows (coalesced 256B per row)
        int ii = tid >> 6, kk = tid & 63;
        tq_s[ii * Kn + kk] = TQ[(b * Ln + i0 + ii) * Kn + kk];
    }

    // thread owns key row j = tid: load c[64], B[64]
    float cr[Kn], Br[Kn];
    const float4* cb4 = (const float4*)(CB + (b * Ln + tid) * 128);
    #pragma unroll
    for (int q = 0; q < 16; ++q) {
        float4 v = cb4[q];
        cr[q * 4 + 0] = v.x; cr[q * 4 + 1] = v.y;
        cr[q * 4 + 2] = v.z; cr[q * 4 + 3] = v.w;
    }
    #pragma unroll
    for (int q = 0; q < 16; ++q) {
        float4 v = cb4[16 + q];
        Br[q * 4 + 0] = v.x; Br[q * 4 + 1] = v.y;
        Br[q * 4 + 2] = v.z; Br[q * 4 + 3] = v.w;
    }
    const float Cjv = Cj[b * Ln + tid];
    __syncthreads();

    // Phase 1: s_i = C_j + sum_k B_k * rcp(tq_ik + c_k)
    float s0 = Cjv, s1 = Cjv, s2 = Cjv, s3 = Cjv;
    const float4* q4a = (const float4*)(tq_s);
    const float4* q4b = (const float4*)(tq_s + Kn);
    const float4* q4c = (const float4*)(tq_s + 2 * Kn);
    const float4* q4d = (const float4*)(tq_s + 3 * Kn);
    #pragma unroll
    for (int k4 = 0; k4 < 16; ++k4) {
        float4 q0 = q4a[k4], q1 = q4b[k4], q2 = q4c[k4], q3 = q4d[k4];
        #pragma unroll
        for (int c = 0; c < 4; ++c) {
            float ck = cr[k4 * 4 + c];
            float Bk = Br[k4 * 4 + c];
            float tq0 = (c == 0) ? q0.x : (c == 1) ? q0.y : (c == 2) ? q0.z : q0.w;
            float tq1 = (c == 0) ? q1.x : (c == 1) ? q1.y : (c == 2) ? q1.z : q1.w;
            float tq2 = (c == 0) ? q2.x : (c == 1) ? q2.y : (c == 2) ? q2.z : q2.w;
            float tq3 = (c == 0) ? q3.x : (c == 1) ? q3.y : (c == 2) ? q3.z : q3.w;
            s0 = fmaf(Bk, __builtin_amdgcn_rcpf(tq0 + ck), s0);
            s1 = fmaf(Bk, __builtin_amdgcn_rcpf(tq1 + ck), s1);
            s2 = fmaf(Bk, __builtin_amdgcn_rcpf(tq2 + ck), s2);
            s3 = fmaf(Bk, __builtin_amdgcn_rcpf(tq3 + ck), s3);
        }
    }
    ((float4*)S)[tid] = make_float4(s0, s1, s2, s3);   // S[j][i]
    __syncthreads();

    // Phase 2: softmax over j; wave wv handles query row i=wv
    {
        const int wv = tid >> 6, lane = tid & 63;
        float v0 = S[(lane      ) * IPB + wv];
        float v1 = S[(lane +  64) * IPB + wv];
        float v2 = S[(lane + 128) * IPB + wv];
        float v3 = S[(lane + 192) * IPB + wv];
        float m = fmaxf(fmaxf(v0, v1), fmaxf(v2, v3));
        #pragma unroll
        for (int off = 32; off > 0; off >>= 1)
            m = fmaxf(m, __shfl_xor(m, off));
        float e0 = __expf(v0 - m), e1 = __expf(v1 - m);
        float e2 = __expf(v2 - m), e3 = __expf(v3 - m);
        float sum = e0 + e1 + e2 + e3;
        #pragma unroll
        for (int off = 32; off > 0; off >>= 1)
            sum += __shfl_xor(sum, off);
        float inv = 1.0f / sum;
        S[(lane      ) * IPB + wv] = e0 * inv;
        S[(lane +  64) * IPB + wv] = e1 * inv;
        S[(lane + 128) * IPB + wv] = e2 * inv;
        S[(lane + 192) * IPB + wv] = e3 * inv;
    }
    __syncthreads();

    // Phase 3: context, j split across waves; float4 X loads, LDS cross-wave reduce
    {
        const int wv = tid >> 6, lane = tid & 63;
        float4 acc0 = {0,0,0,0}, acc1 = {0,0,0,0}, acc2 = {0,0,0,0}, acc3 = {0,0,0,0};
        const float4* Xb4 = (const float4*)(X + b * Ln * Dn);
        const float4* S4  = (const float4*)S;
        const int jbase = wv * 64;
        #pragma unroll 8
        for (int jj = 0; jj < 64; ++jj) {
            int j = jbase + jj;
            float4 at = S4[j];                 // uniform broadcast b128
            float4 x  = Xb4[j * 64 + lane];    // coalesced 1 KB/wave
            acc0.x = fmaf(at.x, x.x, acc0.x); acc0.y = fmaf(at.x, x.y, acc0.y);
            acc0.z = fmaf(at.x, x.z, acc0.z); acc0.w = fmaf(at.x, x.w, acc0.w);
            acc1.x = fmaf(at.y, x.x, acc1.x); acc1.y = fmaf(at.y, x.y, acc1.y);
            acc1.z = fmaf(at.y, x.z, acc1.z); acc1.w = fmaf(at.y, x.w, acc1.w);
            acc2.x = fmaf(at.z, x.x, acc2.x); acc2.y = fmaf(at.z, x.y, acc2.y);
            acc2.z = fmaf(at.z, x.z, acc2.z); acc2.w = fmaf(at.z, x.w, acc2.w);
            acc3.x = fmaf(at.w, x.x, acc3.x); acc3.y = fmaf(at.w, x.y, acc3.y);
            acc3.z = fmaf(at.w, x.z, acc3.z); acc3.w = fmaf(at.w, x.w, acc3.w);
        }
        red[(wv * IPB + 0) * 64 + lane] = acc0;
        red[(wv * IPB + 1) * 64 + lane] = acc1;
        red[(wv * IPB + 2) * 64 + lane] = acc2;
        red[(wv * IPB + 3) * 64 + lane] = acc3;
    }
    __syncthreads();

    // Cross-wave reduce + b128 stores
    {
        const int i = tid >> 6, q = tid & 63;
        float4 p0 = red[(0 * IPB + i) * 64 + q];
        float4 p1 = red[(1 * IPB + i) * 64 + q];
        float4 p2 = red[(2 * IPB + i) * 64 + q];
        float4 p3 = red[(3 * IPB + i) * 64 + q];
        float4 c;
        c.x = (p0.x + p1.x) + (p2.x + p3.x);
        c.y = (p0.y + p1.y) + (p2.y + p3.y);
        c.z = (p0.z + p1.z) + (p2.z + p3.z);
        c.w = (p0.w + p1.w) + (p2.w + p3.w);
        const int row = b * Ln + i0 + i;
        float4 xcopy = ((const float4*)(X + row * Dn))[q];
        ((float4*)(out + row * 2 * Dn))[q]      = xcopy;  // inputs half
        ((float4*)(out + row * 2 * Dn + Dn))[q] = c;      // context half
    }
}

extern "C" void kernel_launch(void* const* d_in, const int* in_sizes, int n_in,
                              void* d_out, int out_size, void* d_ws, size_t ws_size,
                              hipStream_t stream) {
    const float* X  = (const float*)d_in[0];   // (8,256,256)
    const float* W1 = (const float*)d_in[1];   // (64,512)
    const float* W2 = (const float*)d_in[2];   // (1,64)
    float* out = (float*)d_out;                // (8,256,512)

    float* TQ = (float*)d_ws;                              // 2048*64*4  = 512 KB
    float* CB = (float*)((char*)d_ws + (512 << 10));       // 2048*128*4 = 1 MB
    float* Cj = (float*)((char*)d_ws + (1536 << 10));      // 2048*4     = 8 KB

    proj_kernel<<<ROWS / 8, 256, 0, stream>>>(X, W1, W2, TQ, CB, Cj);
    attn_kernel<<<ROWS / IPB, 256, 0, stream>>>(X, TQ, CB, Cj, out);
}

// Round 5
// 84.926 us; speedup vs baseline: 1.0120x; 1.0120x over previous
//
#include <hip/hip_runtime.h>

// SlotAttention: B=8, L=256, D=256, K=64
// out[b,i,:] = concat(inputs[b,i,:], context[b,i,:])
// scores[b,i,j] = sum_k W2[k]*tanh(qi[b,i,k]+kj[b,j,k]); attn = softmax_j; ctx = attn @ inputs[b]
//
// Round-5: revert round-4 (register-pressure regression), keep round-3 form,
// raise IPB 4->8: halves phase-3 L2 traffic (128->64 MB) and tk re-fetch.
// Grid = 256 blocks (1/CU). Scores kept in two 4-wide LDS planes S0/S1 so all
// LDS b128 ops stay in the canonical conflict-free pattern.

#define Bn 8
#define Ln 256
#define Dn 256
#define Kn 64
#define ROWS (Bn*Ln)       // 2048
#define IPB 8              // query rows per block in attn kernel

// ---------------- Kernel A: projection + tanh (round-3 version) ------------
// QK[row][c]: c<64 -> tanh(qi[k=c]), c>=64 -> tanh(kj[k=c-64])
__global__ __launch_bounds__(128) void proj_kernel(
    const float* __restrict__ X,    // (2048,256)
    const float* __restrict__ W1,   // (64,512)
    float* __restrict__ QK)         // (2048,128)
{
    __shared__ float Xs[4 * 256];
    const int tid = threadIdx.x;
    const int r0 = blockIdx.x * 4;

    const float4* Xg4 = (const float4*)(X + r0 * Dn);
    float4* Xs4 = (float4*)Xs;
    #pragma unroll
    for (int idx = tid; idx < 256; idx += 128) Xs4[idx] = Xg4[idx];
    __syncthreads();

    const int k = tid & 63, half = tid >> 6;
    const float4* Wrow = (const float4*)(W1 + k * (2 * Dn) + half * Dn);
    float acc[4] = {0, 0, 0, 0};
    #pragma unroll 8
    for (int d4 = 0; d4 < 64; ++d4) {
        float4 w = Wrow[d4];
        #pragma unroll
        for (int r = 0; r < 4; ++r) {
            float4 x = ((const float4*)(Xs + r * Dn))[d4];  // uniform LDS broadcast
            float a = acc[r];
            a = fmaf(w.x, x.x, a);
            a = fmaf(w.y, x.y, a);
            a = fmaf(w.z, x.z, a);
            a = fmaf(w.w, x.w, a);
            acc[r] = a;
        }
    }
    #pragma unroll
    for (int r = 0; r < 4; ++r) {
        float e = __expf(2.0f * acc[r]);
        float t = 1.0f - 2.0f / (e + 1.0f);
        t = fminf(0.99999988f, fmaxf(-0.99999988f, t));  // keep 1+tq*tk > 0
        QK[(r0 + r) * 128 + tid] = t;
    }
}

// ---------------- Kernel B: scores + softmax + context ----------------
// grid = ROWS/IPB = 256 blocks, 256 threads. Block: rows i0..i0+7 of batch b.
__global__ __launch_bounds__(256) void attn_kernel(
    const float* __restrict__ X,    // (2048,256)
    const float* __restrict__ QK,   // (2048,128) tanh'd
    const float* __restrict__ W2,   // (64,)
    float* __restrict__ out)        // (2048,512)
{
    __shared__ float tq_s[IPB * Kn];        // [i][k], 2 KB
    __shared__ float w2_s[Kn];
    __shared__ float S0[Ln * 4];            // [j][i] for i = 0..3, 4 KB
    __shared__ float S1[Ln * 4];            // [j][i] for i = 4..7, 4 KB
    __shared__ float4 red[4 * IPB * 64];    // [wv][i][dquad], 32 KB

    const int tid = threadIdx.x;
    const int b  = blockIdx.x >> 5;          // / (Ln/IPB) = /32
    const int i0 = (blockIdx.x & 31) * IPB;

    if (tid < Kn) w2_s[tid] = W2[tid];
    #pragma unroll
    for (int e = 0; e < 2; ++e) {           // tq for 8 query rows, coalesced
        int idx = e * 256 + tid;
        int ii = idx >> 6, kk = idx & 63;
        tq_s[idx] = QK[(b * Ln + i0 + ii) * 128 + kk];
    }

    // thread owns key row j = tid: prefetch tk row (64 floats) to registers
    float tkr[Kn];
    const float4* kj4 = (const float4*)(QK + (b * Ln + tid) * 128 + 64);
    #pragma unroll
    for (int q = 0; q < 16; ++q) {
        float4 v = kj4[q];
        tkr[q * 4 + 0] = v.x; tkr[q * 4 + 1] = v.y;
        tkr[q * 4 + 2] = v.z; tkr[q * 4 + 3] = v.w;
    }
    __syncthreads();

    // Phase 1: scores for 8 i's at this j, tanh identity (tq+tk)/(1+tq*tk)
    float s[IPB] = {0, 0, 0, 0, 0, 0, 0, 0};
    const float4* w4 = (const float4*)w2_s;
    #pragma unroll
    for (int k4 = 0; k4 < 16; ++k4) {
        float4 w = w4[k4];
        float4 q[IPB];
        #pragma unroll
        for (int i = 0; i < IPB; ++i)
            q[i] = ((const float4*)(tq_s + i * Kn))[k4];   // uniform b128
        #pragma unroll
        for (int c = 0; c < 4; ++c) {
            float tk = tkr[k4 * 4 + c];
            float wk = (c == 0) ? w.x : (c == 1) ? w.y : (c == 2) ? w.z : w.w;
            #pragma unroll
            for (int i = 0; i < IPB; ++i) {
                float tq = (c == 0) ? q[i].x : (c == 1) ? q[i].y
                         : (c == 2) ? q[i].z : q[i].w;
                float n = tq + tk, d = fmaf(tq, tk, 1.0f);
                s[i] = fmaf(wk, n * __builtin_amdgcn_rcpf(d), s[i]);
            }
        }
    }
    ((float4*)S0)[tid] = make_float4(s[0], s[1], s[2], s[3]);
    ((float4*)S1)[tid] = make_float4(s[4], s[5], s[6], s[7]);
    __syncthreads();

    // Phase 2: softmax over j; wave wv handles rows i=wv (S0) and i=wv+4 (S1)
    {
        const int wv = tid >> 6, lane = tid & 63;
        float v0 = S0[(lane      ) * 4 + wv];
        float v1 = S0[(lane +  64) * 4 + wv];
        float v2 = S0[(lane + 128) * 4 + wv];
        float v3 = S0[(lane + 192) * 4 + wv];
        float u0 = S1[(lane      ) * 4 + wv];
        float u1 = S1[(lane +  64) * 4 + wv];
        float u2 = S1[(lane + 128) * 4 + wv];
        float u3 = S1[(lane + 192) * 4 + wv];
        float mv = fmaxf(fmaxf(v0, v1), fmaxf(v2, v3));
        float mu = fmaxf(fmaxf(u0, u1), fmaxf(u2, u3));
        #pragma unroll
        for (int off = 32; off > 0; off >>= 1) {
            mv = fmaxf(mv, __shfl_xor(mv, off));
            mu = fmaxf(mu, __shfl_xor(mu, off));
        }
        float e0 = __expf(v0 - mv), e1 = __expf(v1 - mv);
        float e2 = __expf(v2 - mv), e3 = __expf(v3 - mv);
        float f0 = __expf(u0 - mu), f1 = __expf(u1 - mu);
        float f2 = __expf(u2 - mu), f3 = __expf(u3 - mu);
        float sv = e0 + e1 + e2 + e3;
        float su = f0 + f1 + f2 + f3;
        #pragma unroll
        for (int off = 32; off > 0; off >>= 1) {
            sv += __shfl_xor(sv, off);
            su += __shfl_xor(su, off);
        }
        float iv = 1.0f / sv, iu = 1.0f / su;
        S0[(lane      ) * 4 + wv] = e0 * iv;
        S0[(lane +  64) * 4 + wv] = e1 * iv;
        S0[(lane + 128) * 4 + wv] = e2 * iv;
        S0[(lane + 192) * 4 + wv] = e3 * iv;
        S1[(lane      ) * 4 + wv] = f0 * iu;
        S1[(lane +  64) * 4 + wv] = f1 * iu;
        S1[(lane + 128) * 4 + wv] = f2 * iu;
        S1[(lane + 192) * 4 + wv] = f3 * iu;
    }
    __syncthreads();

    // Phase 3: context. Wave wv covers j in [wv*64, wv*64+64); lane l covers
    // d = 4l..4l+3. Two uniform b128 attn reads + one coalesced float4 X read/j.
    {
        const int wv = tid >> 6, lane = tid & 63;
        float4 a[IPB];
        #pragma unroll
        for (int i = 0; i < IPB; ++i) a[i] = make_float4(0.f, 0.f, 0.f, 0.f);
        const float4* Xb4 = (const float4*)(X + b * Ln * Dn);
        const float4* S04 = (const float4*)S0;
        const float4* S14 = (const float4*)S1;
        const int jbase = wv * 64;
        #pragma unroll 4
        for (int jj = 0; jj < 64; ++jj) {
            int j = jbase + jj;
            float4 at0 = S04[j];
            float4 at1 = S14[j];
            float4 x   = Xb4[j * 64 + lane];
            a[0].x = fmaf(at0.x, x.x, a[0].x); a[0].y = fmaf(at0.x, x.y, a[0].y);
            a[0].z = fmaf(at0.x, x.z, a[0].z); a[0].w = fmaf(at0.x, x.w, a[0].w);
            a[1].x = fmaf(at0.y, x.x, a[1].x); a[1].y = fmaf(at0.y, x.y, a[1].y);
            a[1].z = fmaf(at0.y, x.z, a[1].z); a[1].w = fmaf(at0.y, x.w, a[1].w);
            a[2].x = fmaf(at0.z, x.x, a[2].x); a[2].y = fmaf(at0.z, x.y, a[2].y);
            a[2].z = fmaf(at0.z, x.z, a[2].z); a[2].w = fmaf(at0.z, x.w, a[2].w);
            a[3].x = fmaf(at0.w, x.x, a[3].x); a[3].y = fmaf(at0.w, x.y, a[3].y);
            a[3].z = fmaf(at0.w, x.z, a[3].z); a[3].w = fmaf(at0.w, x.w, a[3].w);
            a[4].x = fmaf(at1.x, x.x, a[4].x); a[4].y = fmaf(at1.x, x.y, a[4].y);
            a[4].z = fmaf(at1.x, x.z, a[4].z); a[4].w = fmaf(at1.x, x.w, a[4].w);
            a[5].x = fmaf(at1.y, x.x, a[5].x); a[5].y = fmaf(at1.y, x.y, a[5].y);
            a[5].z = fmaf(at1.y, x.z, a[5].z); a[5].w = fmaf(at1.y, x.w, a[5].w);
            a[6].x = fmaf(at1.z, x.x, a[6].x); a[6].y = fmaf(at1.z, x.y, a[6].y);
            a[6].z = fmaf(at1.z, x.z, a[6].z); a[6].w = fmaf(at1.z, x.w, a[6].w);
            a[7].x = fmaf(at1.w, x.x, a[7].x); a[7].y = fmaf(at1.w, x.y, a[7].y);
            a[7].z = fmaf(at1.w, x.z, a[7].z); a[7].w = fmaf(at1.w, x.w, a[7].w);
        }
        #pragma unroll
        for (int i = 0; i < IPB; ++i)
            red[(wv * IPB + i) * 64 + lane] = a[i];
    }
    __syncthreads();

    // Cross-wave reduce + b128 stores: 512 (row,quad) items over 256 threads
    #pragma unroll
    for (int e = 0; e < 2; ++e) {
        const int idx = e * 256 + tid;
        const int i = idx >> 6, q = idx & 63;
        float4 p0 = red[(0 * IPB + i) * 64 + q];
        float4 p1 = red[(1 * IPB + i) * 64 + q];
        float4 p2 = red[(2 * IPB + i) * 64 + q];
        float4 p3 = red[(3 * IPB + i) * 64 + q];
        float4 c;
        c.x = (p0.x + p1.x) + (p2.x + p3.x);
        c.y = (p0.y + p1.y) + (p2.y + p3.y);
        c.z = (p0.z + p1.z) + (p2.z + p3.z);
        c.w = (p0.w + p1.w) + (p2.w + p3.w);
        const int row = b * Ln + i0 + i;
        float4 xcopy = ((const float4*)(X + row * Dn))[q];
        ((float4*)(out + row * 2 * Dn))[q]      = xcopy;  // inputs half
        ((float4*)(out + row * 2 * Dn + Dn))[q] = c;      // context half
    }
}

extern "C" void kernel_launch(void* const* d_in, const int* in_sizes, int n_in,
                              void* d_out, int out_size, void* d_ws, size_t ws_size,
                              hipStream_t stream) {
    const float* X  = (const float*)d_in[0];   // (8,256,256)
    const float* W1 = (const float*)d_in[1];   // (64,512)
    const float* W2 = (const float*)d_in[2];   // (1,64)
    float* out = (float*)d_out;                // (8,256,512)
    float* QK  = (float*)d_ws;                 // (2048,128) = 1 MB scratch

    proj_kernel<<<ROWS / 4, 128, 0, stream>>>(X, W1, QK);
    attn_kernel<<<ROWS / IPB, 256, 0, stream>>>(X, QK, W2, out);
}

// Round 6
// 80.485 us; speedup vs baseline: 1.0679x; 1.0552x over previous
//
#include <hip/hip_runtime.h>

// SlotAttention: B=8, L=256, D=256, K=64
// out[b,i,:] = concat(inputs[b,i,:], context[b,i,:])
// scores[b,i,j] = sum_k W2[k]*tanh(qi[b,i,k]+kj[b,j,k]); attn = softmax_j; ctx = attn @ inputs[b]
//
// Round-6 = round-3 structure (best so far) + exp-product score form:
//   tanh(q+k) = 1 - 2/(e^{2q} e^{2k} + 1)
//   score_i   = W - 2 sum_k w_k * rcp(Eq_ik*Ek_jk + 1),  W = sum_k w_k
// proj stores Eq/Ek (no tanh, no div, no clamp; denom >= 1 always).
// Phase-1 inner: {fma, rcp, fma} vs round-3's {add, fma, rcp, mul, fma}.

#define Bn 8
#define Ln 256
#define Dn 256
#define Kn 64
#define ROWS (Bn*Ln)       // 2048
#define IPB 4              // query rows per block in attn kernel

// ---------------- Kernel A: projection -> exp form ----------------
// QK[row][c]: c<64 -> Eq = e^{2*qi[k=c]}, c>=64 -> Ek = e^{2*kj[k=c-64]}
__global__ __launch_bounds__(128) void proj_kernel(
    const float* __restrict__ X,    // (2048,256)
    const float* __restrict__ W1,   // (64,512)
    float* __restrict__ QK)         // (2048,128)
{
    __shared__ float Xs[4 * 256];
    const int tid = threadIdx.x;
    const int r0 = blockIdx.x * 4;

    const float4* Xg4 = (const float4*)(X + r0 * Dn);
    float4* Xs4 = (float4*)Xs;
    #pragma unroll
    for (int idx = tid; idx < 256; idx += 128) Xs4[idx] = Xg4[idx];
    __syncthreads();

    const int k = tid & 63, half = tid >> 6;
    const float4* Wrow = (const float4*)(W1 + k * (2 * Dn) + half * Dn);
    float acc[4] = {0, 0, 0, 0};
    #pragma unroll 8
    for (int d4 = 0; d4 < 64; ++d4) {
        float4 w = Wrow[d4];
        #pragma unroll
        for (int r = 0; r < 4; ++r) {
            float4 x = ((const float4*)(Xs + r * Dn))[d4];  // uniform LDS broadcast
            float a = acc[r];
            a = fmaf(w.x, x.x, a);
            a = fmaf(w.y, x.y, a);
            a = fmaf(w.z, x.z, a);
            a = fmaf(w.w, x.w, a);
            acc[r] = a;
        }
    }
    #pragma unroll
    for (int r = 0; r < 4; ++r)
        QK[(r0 + r) * 128 + tid] = __expf(2.0f * acc[r]);   // Eq or Ek
}

// ---------------- Kernel B: scores + softmax + context ----------------
// grid = (B*L/IPB) blocks, 256 threads. Block handles rows i0..i0+3 of batch b.
__global__ __launch_bounds__(256) void attn_kernel(
    const float* __restrict__ X,    // (2048,256)
    const float* __restrict__ QK,   // (2048,128) exp'd
    const float* __restrict__ W2,   // (64,)
    float* __restrict__ out)        // (2048,512)
{
    __shared__ float eq_s[IPB * Kn];        // [i][k], 1 KB  (Eq values)
    __shared__ float w2_s[Kn];
    __shared__ float S[Ln * IPB];           // [j][i], 4 KB
    __shared__ float4 red[4 * IPB * 64];    // [wv][i][dquad], 16 KB

    const int tid = threadIdx.x;
    const int b  = blockIdx.x / (Ln / IPB);
    const int i0 = (blockIdx.x % (Ln / IPB)) * IPB;

    if (tid < Kn) w2_s[tid] = W2[tid];
    {   // Eq for the 4 query rows
        int ii = tid >> 6, kk = tid & 63;
        eq_s[ii * Kn + kk] = QK[(b * Ln + i0 + ii) * 128 + kk];
    }

    // thread owns key row j = tid: prefetch Ek row (64 floats) to registers
    float ekr[Kn];
    const float4* kj4 = (const float4*)(QK + (b * Ln + tid) * 128 + 64);
    #pragma unroll
    for (int q = 0; q < 16; ++q) {
        float4 v = kj4[q];
        ekr[q * 4 + 0] = v.x; ekr[q * 4 + 1] = v.y;
        ekr[q * 4 + 2] = v.z; ekr[q * 4 + 3] = v.w;
    }
    __syncthreads();

    // W = sum_k w_k (wave-uniform): one b32 LDS read + 6 shuffles
    float Wsum;
    {
        float v = w2_s[tid & 63];
        #pragma unroll
        for (int off = 32; off > 0; off >>= 1)
            v += __shfl_xor(v, off);
        Wsum = v;
    }

    // Phase 1: T_i = sum_k w_k * rcp(Eq_ik*Ek_k + 1);  score = W - 2*T
    float s[IPB] = {0, 0, 0, 0};
    const float4* w4  = (const float4*)w2_s;
    const float4* q4a = (const float4*)(eq_s);
    const float4* q4b = (const float4*)(eq_s + Kn);
    const float4* q4c = (const float4*)(eq_s + 2 * Kn);
    const float4* q4d = (const float4*)(eq_s + 3 * Kn);
    #pragma unroll
    for (int k4 = 0; k4 < 16; ++k4) {
        float4 w  = w4[k4];
        float4 q0 = q4a[k4], q1 = q4b[k4], q2 = q4c[k4], q3 = q4d[k4];
        #pragma unroll
        for (int c = 0; c < 4; ++c) {
            float ek = ekr[k4 * 4 + c];
            float wk = (c == 0) ? w.x : (c == 1) ? w.y : (c == 2) ? w.z : w.w;
            float e0 = (c == 0) ? q0.x : (c == 1) ? q0.y : (c == 2) ? q0.z : q0.w;
            float e1 = (c == 0) ? q1.x : (c == 1) ? q1.y : (c == 2) ? q1.z : q1.w;
            float e2 = (c == 0) ? q2.x : (c == 1) ? q2.y : (c == 2) ? q2.z : q2.w;
            float e3 = (c == 0) ? q3.x : (c == 1) ? q3.y : (c == 2) ? q3.z : q3.w;
            s[0] = fmaf(wk, __builtin_amdgcn_rcpf(fmaf(e0, ek, 1.0f)), s[0]);
            s[1] = fmaf(wk, __builtin_amdgcn_rcpf(fmaf(e1, ek, 1.0f)), s[1]);
            s[2] = fmaf(wk, __builtin_amdgcn_rcpf(fmaf(e2, ek, 1.0f)), s[2]);
            s[3] = fmaf(wk, __builtin_amdgcn_rcpf(fmaf(e3, ek, 1.0f)), s[3]);
        }
    }
    ((float4*)S)[tid] = make_float4(fmaf(-2.0f, s[0], Wsum),
                                    fmaf(-2.0f, s[1], Wsum),
                                    fmaf(-2.0f, s[2], Wsum),
                                    fmaf(-2.0f, s[3], Wsum));   // S[j][i]
    __syncthreads();

    // Phase 2: softmax over j; wave wv handles query row i=wv
    {
        const int wv = tid >> 6, lane = tid & 63;
        float v0 = S[(lane      ) * IPB + wv];
        float v1 = S[(lane +  64) * IPB + wv];
        float v2 = S[(lane + 128) * IPB + wv];
        float v3 = S[(lane + 192) * IPB + wv];
        float m = fmaxf(fmaxf(v0, v1), fmaxf(v2, v3));
        #pragma unroll
        for (int off = 32; off > 0; off >>= 1)
            m = fmaxf(m, __shfl_xor(m, off));
        float e0 = __expf(v0 - m), e1 = __expf(v1 - m);
        float e2 = __expf(v2 - m), e3 = __expf(v3 - m);
        float sum = e0 + e1 + e2 + e3;
        #pragma unroll
        for (int off = 32; off > 0; off >>= 1)
            sum += __shfl_xor(sum, off);
        float inv = 1.0f / sum;
        S[(lane      ) * IPB + wv] = e0 * inv;
        S[(lane +  64) * IPB + wv] = e1 * inv;
        S[(lane + 128) * IPB + wv] = e2 * inv;
        S[(lane + 192) * IPB + wv] = e3 * inv;
    }
    __syncthreads();

    // Phase 3: context, j split across waves; float4 X loads, LDS cross-wave reduce
    {
        const int wv = tid >> 6, lane = tid & 63;
        float4 acc0 = {0,0,0,0}, acc1 = {0,0,0,0}, acc2 = {0,0,0,0}, acc3 = {0,0,0,0};
        const float4* Xb4 = (const float4*)(X + b * Ln * Dn);
        const float4* S4  = (const float4*)S;
        const int jbase = wv * 64;
        #pragma unroll 8
        for (int jj = 0; jj < 64; ++jj) {
            int j = jbase + jj;
            float4 at = S4[j];                 // uniform broadcast b128
            float4 x  = Xb4[j * 64 + lane];    // coalesced 1 KB/wave
            acc0.x = fmaf(at.x, x.x, acc0.x); acc0.y = fmaf(at.x, x.y, acc0.y);
            acc0.z = fmaf(at.x, x.z, acc0.z); acc0.w = fmaf(at.x, x.w, acc0.w);
            acc1.x = fmaf(at.y, x.x, acc1.x); acc1.y = fmaf(at.y, x.y, acc1.y);
            acc1.z = fmaf(at.y, x.z, acc1.z); acc1.w = fmaf(at.y, x.w, acc1.w);
            acc2.x = fmaf(at.z, x.x, acc2.x); acc2.y = fmaf(at.z, x.y, acc2.y);
            acc2.z = fmaf(at.z, x.z, acc2.z); acc2.w = fmaf(at.z, x.w, acc2.w);
            acc3.x = fmaf(at.w, x.x, acc3.x); acc3.y = fmaf(at.w, x.y, acc3.y);
            acc3.z = fmaf(at.w, x.z, acc3.z); acc3.w = fmaf(at.w, x.w, acc3.w);
        }
        red[(wv * IPB + 0) * 64 + lane] = acc0;
        red[(wv * IPB + 1) * 64 + lane] = acc1;
        red[(wv * IPB + 2) * 64 + lane] = acc2;
        red[(wv * IPB + 3) * 64 + lane] = acc3;
    }
    __syncthreads();

    // Cross-wave reduce + b128 stores
    {
        const int i = tid >> 6, q = tid & 63;
        float4 p0 = red[(0 * IPB + i) * 64 + q];
        float4 p1 = red[(1 * IPB + i) * 64 + q];
        float4 p2 = red[(2 * IPB + i) * 64 + q];
        float4 p3 = red[(3 * IPB + i) * 64 + q];
        float4 c;
        c.x = (p0.x + p1.x) + (p2.x + p3.x);
        c.y = (p0.y + p1.y) + (p2.y + p3.y);
        c.z = (p0.z + p1.z) + (p2.z + p3.z);
        c.w = (p0.w + p1.w) + (p2.w + p3.w);
        const int row = b * Ln + i0 + i;
        float4 xcopy = ((const float4*)(X + row * Dn))[q];
        ((float4*)(out + row * 2 * Dn))[q]      = xcopy;  // inputs half
        ((float4*)(out + row * 2 * Dn + Dn))[q] = c;      // context half
    }
}

extern "C" void kernel_launch(void* const* d_in, const int* in_sizes, int n_in,
                              void* d_out, int out_size, void* d_ws, size_t ws_size,
                              hipStream_t stream) {
    const float* X  = (const float*)d_in[0];   // (8,256,256)
    const float* W1 = (const float*)d_in[1];   // (64,512)
    const float* W2 = (const float*)d_in[2];   // (1,64)
    float* out = (float*)d_out;                // (8,256,512)
    float* QK  = (float*)d_ws;                 // (2048,128) = 1 MB scratch

    proj_kernel<<<ROWS / 4, 128, 0, stream>>>(X, W1, QK);
    attn_kernel<<<ROWS / IPB, 256, 0, stream>>>(X, QK, W2, out);
}